// Round 9
// baseline (374.935 us; speedup 1.0000x reference)
//
#include <hip/hip_runtime.h>
#include <math.h>

// Variance-gamma MC option pricer — R8: two 32-lane scans per wave.
// Keeps R4's winning ingredients (direct coalesced dword loads, DPP scan, no
// LDS staging, no hot-loop barriers) and halves the scan cost: lanes 0-31
// carry path A's steps, lanes 32-63 path B's, in 32-step chunks. 32-wide
// inclusive scan = 5 DPP adds (row_shr 1/2/4/8 + row_bcast:15 masked 0xa);
// halves independent. Segment boundaries 30m-1 land at static lane 29-2c
// (exactly one per chunk, c=0..11); prefix at that lane is unaffected by any
// garbage beyond it, so no masking anywhere. All 24 loads per wave issue
// up-front from one address reg + imm offsets -> deep memory pipeline.
// Chunk 11 (steps 352..383) uses a clamped address (last path overruns row).
// Puts derived at finalize from call tables + sum(S) (proven R3-R7).

#define NSTEPS 365
#define NM     12
#define NK     21
#define BLOCK  512
#define WPB    (BLOCK / 64)      // 8 waves
#define PPB    (2 * WPB)         // 16 paths per block
#define NCELL  (NM * NK)         // 252
#define WSZ    (2 * NCELL + NM)  // call@Kc, call@Kp, sumS -> 516

#define THETA_F (-0.1436f)
#define SIGMA_F (0.1213f)
#define THETA_D (-0.1436)
#define MU_D    (0.1686)
#define SIGMA_D (0.1213)
#define LOG2E_F (1.4426950408889634f)

template <int CTRL, int RMASK>
__device__ __forceinline__ float dpp_add(float v) {
    const int t = __builtin_amdgcn_update_dpp(0, __float_as_int(v), CTRL, RMASK, 0xf, true);
    return v + __int_as_float(t);
}
// Independent inclusive scans over lanes 0-31 and 32-63.
__device__ __forceinline__ float scan32(float v) {
    v = dpp_add<0x111, 0xf>(v);   // row_shr:1
    v = dpp_add<0x112, 0xf>(v);   // row_shr:2
    v = dpp_add<0x114, 0xf>(v);   // row_shr:4
    v = dpp_add<0x118, 0xf>(v);   // row_shr:8
    v = dpp_add<0x142, 0xa>(v);   // row_bcast:15 -> rows 1,3 (stay within halves)
    return v;
}
__device__ __forceinline__ float rdlane(float v, int l) {
    return __int_as_float(__builtin_amdgcn_readlane(__float_as_int(v), l));
}
__device__ __forceinline__ float rfl(float v) {
    return __int_as_float(__builtin_amdgcn_readfirstlane(__float_as_int(v)));
}

__global__ __launch_bounds__(BLOCK, 6) void vg_paths_kernel(
    const float* __restrict__ S0p, const float* __restrict__ ratep,
    const int* __restrict__ indices, const float* __restrict__ z,
    const float* __restrict__ gam, const float* __restrict__ Kc,
    const float* __restrict__ Kp, float* __restrict__ acc, int MC)
{
    __shared__ float lacc[WSZ];
    const int tid = threadIdx.x;
    for (int i = tid; i < WSZ; i += BLOCK) lacc[i] = 0.f;
    __syncthreads();

    const int lane = tid & 63;
    const int wv   = tid >> 6;
    const int l31  = lane & 31;

    const int pA = blockIdx.x * PPB + 2 * wv;
    const int pB = pA + 1;
    const int pc = min((lane < 32) ? pA : pB, MC - 1);

    const float r_  = ratep[0];
    const float s0_ = S0p[0];
    const float w   = (float)((1.0 / MU_D) *
                      log(1.0 - THETA_D * MU_D - SIGMA_D * SIGMA_D * MU_D / 2.0));
    const float th2  = THETA_F * LOG2E_F;
    const float sg2  = SIGMA_F * LOG2E_F;
    const float rwh2 = (r_ + w) * LOG2E_F / (float)NSTEPS;
    const float l2s0 = log2f(s0_);

    float ab2[NM];                          // wave-uniform
    #pragma unroll
    for (int m = 0; m < NM; ++m) ab2[m] = rfl(rwh2 * (float)indices[m] + l2s0);

    // ---- all 24 loads up-front: one base addr + imm offsets ----
    const size_t ibase = (size_t)pc * NSTEPS + l31;
    const size_t gmaxi = (size_t)MC * NSTEPS - 1;
    const float* zr = z   + ibase;
    const float* gr = gam + ibase;
    const size_t i11 = (ibase + 352 > gmaxi) ? gmaxi : ibase + 352;  // last-path clamp

    float zv[12], gv[12];
    #pragma unroll
    for (int c = 0; c < 11; ++c) { zv[c] = zr[32 * c]; gv[c] = gr[32 * c]; }
    zv[11] = z[i11]; gv[11] = gam[i11];

    // ---- 12 chunks: prep + scan32 + boundary/carry extraction ----
    float XA[NM], XB[NM];
    float cA = 0.f, cB = 0.f;
    #pragma unroll
    for (int c = 0; c < 12; ++c) {
        const float g = gv[c];
        float v = fmaf(th2, g, sg2 * (sqrtf(g) * zv[c]));
        v = scan32(v);
        XA[c] = cA + rdlane(v, 29 - 2 * c);       // boundary 30(c+1)-1, half A
        XB[c] = cB + rdlane(v, 61 - 2 * c);       // same, half B
        if (c < 11) {
            cA += rdlane(v, 31);
            cB += rdlane(v, 63);
        }
    }

    // ---- payoff: lane=(mg,k), both paths wave-uniform ----
    const int k  = lane % NK;
    const int mg = lane / NK;                     // 0..2 (lane 63 -> 3, dummy)
    const float kc = Kc[k], kp = Kp[k];
    float ac_c[4] = {0.f, 0.f, 0.f, 0.f};
    float ac_p[4] = {0.f, 0.f, 0.f, 0.f};
    float sS4[4]  = {0.f, 0.f, 0.f, 0.f};

    #define VG_ACCUM(X, pv)                                                   \
    do {                                                                      \
        if (pv) {                                                             \
            float S[NM];                                                      \
            _Pragma("unroll")                                                 \
            for (int m = 0; m < NM; ++m) S[m] = exp2f(ab2[m] + (X)[m]);       \
            _Pragma("unroll")                                                 \
            for (int j = 0; j < 4; ++j) {                                     \
                const float Sj = (mg == 0) ? S[j]                             \
                               : (mg == 1) ? S[j + 4] : S[j + 8];             \
                ac_c[j] += fmaxf(Sj - kc, 0.f);                               \
                ac_p[j] += fmaxf(Sj - kp, 0.f);                               \
                sS4[j]  += Sj;                                                \
            }                                                                 \
        }                                                                     \
    } while (0)
    VG_ACCUM(XA, pA < MC);
    VG_ACCUM(XB, pB < MC);
    #undef VG_ACCUM

    // ---- block reduce: regs -> LDS -> global atomics ----
    if (lane < 63) {
        #pragma unroll
        for (int j = 0; j < 4; ++j) {
            const int cell = (4 * mg + j) * NK + k;
            atomicAdd(&lacc[cell],         ac_c[j]);
            atomicAdd(&lacc[NCELL + cell], ac_p[j]);
        }
        if (k == 0) {
            #pragma unroll
            for (int j = 0; j < 4; ++j)
                atomicAdd(&lacc[2 * NCELL + 4 * mg + j], sS4[j]);
        }
    }
    __syncthreads();
    for (int i = tid; i < WSZ; i += BLOCK)
        atomicAdd(&acc[i], lacc[i]);
}

__global__ void vg_finalize_kernel(const float* __restrict__ acc,
                                   const float* __restrict__ ratep,
                                   const int* __restrict__ indices,
                                   const float* __restrict__ Kc,
                                   const float* __restrict__ Kp,
                                   float* __restrict__ out, int MC)
{
    const int i = blockIdx.x * blockDim.x + threadIdx.x;
    if (i >= 4 * NCELL) return;
    const int t    = i / NCELL;
    const int cell = i % NCELL;
    const int m    = cell / NK;
    const int kk   = cell % NK;
    const float r_   = ratep[0];
    const float im   = (float)indices[m];
    const float disc = expf(-r_ * im / (float)NSTEPS);
    const float cc = acc[cell];              // sum max(S-Kc,0)
    const float cp = acc[NCELL + cell];      // sum max(S-Kp,0)
    const float sS = acc[2 * NCELL + m];     // sum S
    const float fM = (float)MC;
    float v;
    if      (t == 0) v = cc;                          // call @ Kc
    else if (t == 1) v = cp - sS + fM * Kp[kk];       // put  @ Kp
    else if (t == 2) v = cp;                          // call @ Kp
    else             v = cc - sS + fM * Kc[kk];       // put  @ Kc
    out[i] = disc * v / fM;
}

extern "C" void kernel_launch(void* const* d_in, const int* in_sizes, int n_in,
                              void* d_out, int out_size, void* d_ws, size_t ws_size,
                              hipStream_t stream) {
    const float* S0      = (const float*)d_in[0];
    const float* rate    = (const float*)d_in[1];
    const int*   indices = (const int*)d_in[2];
    const float* z       = (const float*)d_in[3];
    const float* gamma_  = (const float*)d_in[4];
    const float* Kc      = (const float*)d_in[5];
    const float* Kp      = (const float*)d_in[6];

    const int MC = in_sizes[3] / NSTEPS;
    float* acc = (float*)d_ws;

    (void)hipMemsetAsync(d_ws, 0, WSZ * sizeof(float), stream);

    const int nb = (MC + PPB - 1) / PPB;
    vg_paths_kernel<<<nb, BLOCK, 0, stream>>>(S0, rate, indices, z, gamma_, Kc, Kp, acc, MC);

    vg_finalize_kernel<<<(4 * NCELL + 255) / 256, 256, 0, stream>>>(
        acc, rate, indices, Kc, Kp, (float*)d_out, MC);
}

// Round 10
// 197.380 us; speedup vs baseline: 1.8996x; 1.8996x over previous
//
#include <hip/hip_runtime.h>
#include <math.h>

// Variance-gamma MC option pricer — R9: R4 skeleton + raw-instruction math.
// R4 (213us, best) audit: library sqrtf ~10 instr (IEEE fixup), exp2f ~7,
// 12 wave-uniform exps/path, payoff selects -> ~640 SIMD-cyc/path VALU.
// R9 keeps R4's proven structure EXACTLY (wave=path, 64-step chunks, DPP
// scan, readlane boundaries, pair double-buffered loads, block reduce,
// puts-derived finalize) and swaps: sqrtf -> __builtin_amdgcn_sqrtf (1
// instr), exp2 -> __builtin_amdgcn_exp2f (1 instr, log2-domain coeffs),
// and selects X BEFORE exp (per-lane abj[4] hoisted: 4 exps not 12).

#define NSTEPS 365
#define NM     12
#define NK     21
#define PPW    8             // paths per wave
#define WAVES  4
#define BLOCK  (WAVES * 64)
#define PPB    (WAVES * PPW) // 32 paths per block

#define NCELL  (NM * NK)         // 252
#define WSZ    (2 * NCELL + NM)  // call@Kc, call@Kp, sumS -> 516

#define THETA_F (-0.1436f)
#define SIGMA_F (0.1213f)
#define THETA_D (-0.1436)
#define MU_D    (0.1686)
#define SIGMA_D (0.1213)
#define LOG2E_F (1.4426950408889634f)

template <int CTRL, int RMASK>
__device__ __forceinline__ float dpp_add(float v) {
    const int t = __builtin_amdgcn_update_dpp(0, __float_as_int(v), CTRL, RMASK, 0xf, true);
    return v + __int_as_float(t);
}
__device__ __forceinline__ float scan64(float v) {
    v = dpp_add<0x111, 0xf>(v);   // row_shr:1
    v = dpp_add<0x112, 0xf>(v);   // row_shr:2
    v = dpp_add<0x114, 0xf>(v);   // row_shr:4
    v = dpp_add<0x118, 0xf>(v);   // row_shr:8
    v = dpp_add<0x142, 0xa>(v);   // row_bcast:15 -> rows 1,3
    v = dpp_add<0x143, 0xc>(v);   // row_bcast:31 -> rows 2,3
    return v;
}
__device__ __forceinline__ float rdlane(float v, int l) {
    return __int_as_float(__builtin_amdgcn_readlane(__float_as_int(v), l));
}
__device__ __forceinline__ float rfl(float v) {
    return __int_as_float(__builtin_amdgcn_readfirstlane(__float_as_int(v)));
}

__global__ __launch_bounds__(BLOCK) void vg_paths_kernel(
    const float* __restrict__ S0p, const float* __restrict__ ratep,
    const int* __restrict__ indices, const float* __restrict__ z,
    const float* __restrict__ gam, const float* __restrict__ Kc,
    const float* __restrict__ Kp, float* __restrict__ acc, int MC)
{
    __shared__ float lacc[WSZ];
    const int tid = threadIdx.x;
    for (int i = tid; i < WSZ; i += BLOCK) lacc[i] = 0.f;
    __syncthreads();

    const int lane = tid & 63;
    const int wv   = tid >> 6;
    const int k    = lane % NK;          // strike col (lane 63 dummy)
    const int mg   = lane / NK;          // maturity group 0..2 (lane 63 -> 3)
    const int mgc  = (mg > 2) ? 2 : mg;

    const float kc  = Kc[k];
    const float kp  = Kp[k];
    const float r_  = ratep[0];
    const float s0_ = S0p[0];
    const float w   = (float)((1.0 / MU_D) *
                      log(1.0 - THETA_D * MU_D - SIGMA_D * SIGMA_D * MU_D / 2.0));
    // log2 domain: S = exp2(ab2[m] + X[m]), incr coeffs scaled by log2(e)
    const float th2  = THETA_F * LOG2E_F;
    const float sg2  = SIGMA_F * LOG2E_F;
    const float rwh2 = (r_ + w) * LOG2E_F / (float)NSTEPS;
    const float l2s0 = log2f(s0_);

    float ab2[NM];                        // wave-uniform
    #pragma unroll
    for (int m = 0; m < NM; ++m) ab2[m] = rfl(rwh2 * (float)indices[m] + l2s0);
    float abj[4];                         // per-lane slice: ab2[4*mgc + j]
    #pragma unroll
    for (int j = 0; j < 4; ++j) abj[j] = ab2[4 * mgc + j];

    float ac_c[4], ac_p[4], sS4[4];
    #pragma unroll
    for (int j = 0; j < 4; ++j) { ac_c[j] = 0.f; ac_p[j] = 0.f; sS4[j] = 0.f; }

    const int o5 = min(lane + 320, 364);  // row-end clamp (dupes masked in scan)
    const bool m5 = (lane < 45);          // chunk-5 valid-lane mask

    auto loadp = [&](int p, float* zv, float* gv) {
        const int pc = min(p, MC - 1);
        const float* zp = z   + (size_t)pc * NSTEPS;
        const float* gp = gam + (size_t)pc * NSTEPS;
        #pragma unroll
        for (int c = 0; c < 5; ++c) {
            zv[c] = zp[lane + 64 * c];
            gv[c] = gp[lane + 64 * c];
        }
        zv[5] = zp[o5]; gv[5] = gp[o5];
    };

    auto process = [&](const float* zv, const float* gv, bool pv) {
        float X[NM];
        float carry = 0.f;
        #pragma unroll
        for (int c = 0; c < 6; ++c) {
            const float g = gv[c];
            float v = fmaf(th2, g, sg2 * (__builtin_amdgcn_sqrtf(g) * zv[c]));
            if (c == 5) v = m5 ? v : 0.f;
            v = scan64(v);
            X[2 * c]     = carry + rdlane(v, 29 - 4 * c);
            X[2 * c + 1] = carry + rdlane(v, 59 - 4 * c);
            carry       += rdlane(v, 63);
        }
        if (!pv) return;                        // wave-uniform guard
        #pragma unroll
        for (int j = 0; j < 4; ++j) {           // select X first, then 1-instr exp2
            const float Xj = (mg == 0) ? X[j] : (mg == 1) ? X[j + 4] : X[j + 8];
            const float Sj = __builtin_amdgcn_exp2f(abj[j] + Xj);
            ac_c[j] += fmaxf(Sj - kc, 0.f);
            ac_p[j] += fmaxf(Sj - kp, 0.f);
            sS4[j]  += Sj;
        }
    };

    // ---- double-buffered path loop (R4-proven) ----
    const int p0 = blockIdx.x * PPB + wv * PPW;
    float zA[6], gA[6], zB[6], gB[6];
    loadp(p0, zA, gA);
    #pragma unroll 1
    for (int pp = 0; pp < PPW; pp += 2) {
        loadp(p0 + pp + 1, zB, gB);
        process(zA, gA, p0 + pp < MC);
        loadp(p0 + pp + 2, zA, gA);          // overrun clamped, result discarded
        process(zB, gB, p0 + pp + 1 < MC);
    }

    // ---- block reduce: regs -> LDS -> global atomics ----
    if (lane < 63) {
        #pragma unroll
        for (int j = 0; j < 4; ++j) {
            const int cell = (4 * mg + j) * NK + k;
            atomicAdd(&lacc[cell],         ac_c[j]);
            atomicAdd(&lacc[NCELL + cell], ac_p[j]);
        }
        if (k == 0) {
            #pragma unroll
            for (int j = 0; j < 4; ++j)
                atomicAdd(&lacc[2 * NCELL + 4 * mg + j], sS4[j]);
        }
    }
    __syncthreads();
    for (int i = tid; i < WSZ; i += BLOCK)
        atomicAdd(&acc[i], lacc[i]);
}

__global__ void vg_finalize_kernel(const float* __restrict__ acc,
                                   const float* __restrict__ ratep,
                                   const int* __restrict__ indices,
                                   const float* __restrict__ Kc,
                                   const float* __restrict__ Kp,
                                   float* __restrict__ out, int MC)
{
    const int i = blockIdx.x * blockDim.x + threadIdx.x;
    if (i >= 4 * NCELL) return;
    const int t    = i / NCELL;
    const int cell = i % NCELL;
    const int m    = cell / NK;
    const int kk   = cell % NK;
    const float r_   = ratep[0];
    const float im   = (float)indices[m];
    const float disc = expf(-r_ * im / (float)NSTEPS);
    const float cc = acc[cell];              // sum max(S-Kc,0)
    const float cp = acc[NCELL + cell];      // sum max(S-Kp,0)
    const float sS = acc[2 * NCELL + m];     // sum S
    const float fM = (float)MC;
    float v;
    if      (t == 0) v = cc;                          // call @ Kc
    else if (t == 1) v = cp - sS + fM * Kp[kk];       // put  @ Kp
    else if (t == 2) v = cp;                          // call @ Kp
    else             v = cc - sS + fM * Kc[kk];       // put  @ Kc
    out[i] = disc * v / fM;
}

extern "C" void kernel_launch(void* const* d_in, const int* in_sizes, int n_in,
                              void* d_out, int out_size, void* d_ws, size_t ws_size,
                              hipStream_t stream) {
    const float* S0      = (const float*)d_in[0];
    const float* rate    = (const float*)d_in[1];
    const int*   indices = (const int*)d_in[2];
    const float* z       = (const float*)d_in[3];
    const float* gamma_  = (const float*)d_in[4];
    const float* Kc      = (const float*)d_in[5];
    const float* Kp      = (const float*)d_in[6];

    const int MC = in_sizes[3] / NSTEPS;
    float* acc = (float*)d_ws;

    (void)hipMemsetAsync(d_ws, 0, WSZ * sizeof(float), stream);

    const int nb = (MC + PPB - 1) / PPB;
    vg_paths_kernel<<<nb, BLOCK, 0, stream>>>(S0, rate, indices, z, gamma_, Kc, Kp, acc, MC);

    vg_finalize_kernel<<<(4 * NCELL + 255) / 256, 256, 0, stream>>>(
        acc, rate, indices, Kc, Kp, (float*)d_out, MC);
}

// Round 11
// 196.365 us; speedup vs baseline: 1.9094x; 1.0052x over previous
//
#include <hip/hip_runtime.h>
#include <math.h>

// Variance-gamma MC option pricer — R10: R9 + sched_barrier-pinned prefetch.
// R9 diagnosis: VGPR=32 -> compiler sank the double-buffered loads to their
// uses (live-range shortening for occupancy), serializing 12 full-latency
// loads per path (~14.4K cyc stall/path, matches 15K measured wall). R10:
// __builtin_amdgcn_sched_barrier(0) after each loadp pins all 12 next-path
// loads BEFORE current-path compute (nothing may cross the fence), and
// __launch_bounds__(256,4) raises the VGPR cap to 128 so both path buffers
// stay live. Everything else identical to R9 (wave=path, DPP scan, raw
// sqrt/exp2, puts derived at finalize).

#define NSTEPS 365
#define NM     12
#define NK     21
#define PPW    8             // paths per wave
#define WAVES  4
#define BLOCK  (WAVES * 64)
#define PPB    (WAVES * PPW) // 32 paths per block

#define NCELL  (NM * NK)         // 252
#define WSZ    (2 * NCELL + NM)  // call@Kc, call@Kp, sumS -> 516

#define THETA_F (-0.1436f)
#define SIGMA_F (0.1213f)
#define THETA_D (-0.1436)
#define MU_D    (0.1686)
#define SIGMA_D (0.1213)
#define LOG2E_F (1.4426950408889634f)

template <int CTRL, int RMASK>
__device__ __forceinline__ float dpp_add(float v) {
    const int t = __builtin_amdgcn_update_dpp(0, __float_as_int(v), CTRL, RMASK, 0xf, true);
    return v + __int_as_float(t);
}
__device__ __forceinline__ float scan64(float v) {
    v = dpp_add<0x111, 0xf>(v);   // row_shr:1
    v = dpp_add<0x112, 0xf>(v);   // row_shr:2
    v = dpp_add<0x114, 0xf>(v);   // row_shr:4
    v = dpp_add<0x118, 0xf>(v);   // row_shr:8
    v = dpp_add<0x142, 0xa>(v);   // row_bcast:15 -> rows 1,3
    v = dpp_add<0x143, 0xc>(v);   // row_bcast:31 -> rows 2,3
    return v;
}
__device__ __forceinline__ float rdlane(float v, int l) {
    return __int_as_float(__builtin_amdgcn_readlane(__float_as_int(v), l));
}
__device__ __forceinline__ float rfl(float v) {
    return __int_as_float(__builtin_amdgcn_readfirstlane(__float_as_int(v)));
}

__global__ __launch_bounds__(BLOCK, 4) void vg_paths_kernel(
    const float* __restrict__ S0p, const float* __restrict__ ratep,
    const int* __restrict__ indices, const float* __restrict__ z,
    const float* __restrict__ gam, const float* __restrict__ Kc,
    const float* __restrict__ Kp, float* __restrict__ acc, int MC)
{
    __shared__ float lacc[WSZ];
    const int tid = threadIdx.x;
    for (int i = tid; i < WSZ; i += BLOCK) lacc[i] = 0.f;
    __syncthreads();

    const int lane = tid & 63;
    const int wv   = tid >> 6;
    const int k    = lane % NK;          // strike col (lane 63 dummy)
    const int mg   = lane / NK;          // maturity group 0..2 (lane 63 -> 3)
    const int mgc  = (mg > 2) ? 2 : mg;

    const float kc  = Kc[k];
    const float kp  = Kp[k];
    const float r_  = ratep[0];
    const float s0_ = S0p[0];
    const float w   = (float)((1.0 / MU_D) *
                      log(1.0 - THETA_D * MU_D - SIGMA_D * SIGMA_D * MU_D / 2.0));
    // log2 domain: S = exp2(ab2[m] + X[m]), incr coeffs scaled by log2(e)
    const float th2  = THETA_F * LOG2E_F;
    const float sg2  = SIGMA_F * LOG2E_F;
    const float rwh2 = (r_ + w) * LOG2E_F / (float)NSTEPS;
    const float l2s0 = log2f(s0_);

    float ab2[NM];                        // wave-uniform
    #pragma unroll
    for (int m = 0; m < NM; ++m) ab2[m] = rfl(rwh2 * (float)indices[m] + l2s0);
    float abj[4];                         // per-lane slice: ab2[4*mgc + j]
    #pragma unroll
    for (int j = 0; j < 4; ++j) abj[j] = ab2[4 * mgc + j];

    float ac_c[4], ac_p[4], sS4[4];
    #pragma unroll
    for (int j = 0; j < 4; ++j) { ac_c[j] = 0.f; ac_p[j] = 0.f; sS4[j] = 0.f; }

    const int o5 = min(lane + 320, 364);  // row-end clamp (dupes masked in scan)
    const bool m5 = (lane < 45);          // chunk-5 valid-lane mask

    auto loadp = [&](int p, float* zv, float* gv) {
        const int pc = min(p, MC - 1);
        const float* zp = z   + (size_t)pc * NSTEPS;
        const float* gp = gam + (size_t)pc * NSTEPS;
        #pragma unroll
        for (int c = 0; c < 5; ++c) {
            zv[c] = zp[lane + 64 * c];
            gv[c] = gp[lane + 64 * c];
        }
        zv[5] = zp[o5]; gv[5] = gp[o5];
    };

    auto process = [&](const float* zv, const float* gv, bool pv) {
        float X[NM];
        float carry = 0.f;
        #pragma unroll
        for (int c = 0; c < 6; ++c) {
            const float g = gv[c];
            float v = fmaf(th2, g, sg2 * (__builtin_amdgcn_sqrtf(g) * zv[c]));
            if (c == 5) v = m5 ? v : 0.f;
            v = scan64(v);
            X[2 * c]     = carry + rdlane(v, 29 - 4 * c);
            X[2 * c + 1] = carry + rdlane(v, 59 - 4 * c);
            carry       += rdlane(v, 63);
        }
        if (!pv) return;                        // wave-uniform guard
        #pragma unroll
        for (int j = 0; j < 4; ++j) {           // select X first, then 1-instr exp2
            const float Xj = (mg == 0) ? X[j] : (mg == 1) ? X[j + 4] : X[j + 8];
            const float Sj = __builtin_amdgcn_exp2f(abj[j] + Xj);
            ac_c[j] += fmaxf(Sj - kc, 0.f);
            ac_p[j] += fmaxf(Sj - kp, 0.f);
            sS4[j]  += Sj;
        }
    };

    // ---- double-buffered path loop; fences pin load issue before compute ----
    const int p0 = blockIdx.x * PPB + wv * PPW;
    float zA[6], gA[6], zB[6], gB[6];
    loadp(p0, zA, gA);
    __builtin_amdgcn_sched_barrier(0);
    #pragma unroll 1
    for (int pp = 0; pp < PPW; pp += 2) {
        loadp(p0 + pp + 1, zB, gB);
        __builtin_amdgcn_sched_barrier(0);   // B-loads issued before process(A)
        process(zA, gA, p0 + pp < MC);
        __builtin_amdgcn_sched_barrier(0);
        loadp(p0 + pp + 2, zA, gA);          // overrun clamped, result discarded
        __builtin_amdgcn_sched_barrier(0);   // A-loads issued before process(B)
        process(zB, gB, p0 + pp + 1 < MC);
        __builtin_amdgcn_sched_barrier(0);
    }

    // ---- block reduce: regs -> LDS -> global atomics ----
    if (lane < 63) {
        #pragma unroll
        for (int j = 0; j < 4; ++j) {
            const int cell = (4 * mg + j) * NK + k;
            atomicAdd(&lacc[cell],         ac_c[j]);
            atomicAdd(&lacc[NCELL + cell], ac_p[j]);
        }
        if (k == 0) {
            #pragma unroll
            for (int j = 0; j < 4; ++j)
                atomicAdd(&lacc[2 * NCELL + 4 * mg + j], sS4[j]);
        }
    }
    __syncthreads();
    for (int i = tid; i < WSZ; i += BLOCK)
        atomicAdd(&acc[i], lacc[i]);
}

__global__ void vg_finalize_kernel(const float* __restrict__ acc,
                                   const float* __restrict__ ratep,
                                   const int* __restrict__ indices,
                                   const float* __restrict__ Kc,
                                   const float* __restrict__ Kp,
                                   float* __restrict__ out, int MC)
{
    const int i = blockIdx.x * blockDim.x + threadIdx.x;
    if (i >= 4 * NCELL) return;
    const int t    = i / NCELL;
    const int cell = i % NCELL;
    const int m    = cell / NK;
    const int kk   = cell % NK;
    const float r_   = ratep[0];
    const float im   = (float)indices[m];
    const float disc = expf(-r_ * im / (float)NSTEPS);
    const float cc = acc[cell];              // sum max(S-Kc,0)
    const float cp = acc[NCELL + cell];      // sum max(S-Kp,0)
    const float sS = acc[2 * NCELL + m];     // sum S
    const float fM = (float)MC;
    float v;
    if      (t == 0) v = cc;                          // call @ Kc
    else if (t == 1) v = cp - sS + fM * Kp[kk];       // put  @ Kp
    else if (t == 2) v = cp;                          // call @ Kp
    else             v = cc - sS + fM * Kc[kk];       // put  @ Kc
    out[i] = disc * v / fM;
}

extern "C" void kernel_launch(void* const* d_in, const int* in_sizes, int n_in,
                              void* d_out, int out_size, void* d_ws, size_t ws_size,
                              hipStream_t stream) {
    const float* S0      = (const float*)d_in[0];
    const float* rate    = (const float*)d_in[1];
    const int*   indices = (const int*)d_in[2];
    const float* z       = (const float*)d_in[3];
    const float* gamma_  = (const float*)d_in[4];
    const float* Kc      = (const float*)d_in[5];
    const float* Kp      = (const float*)d_in[6];

    const int MC = in_sizes[3] / NSTEPS;
    float* acc = (float*)d_ws;

    (void)hipMemsetAsync(d_ws, 0, WSZ * sizeof(float), stream);

    const int nb = (MC + PPB - 1) / PPB;
    vg_paths_kernel<<<nb, BLOCK, 0, stream>>>(S0, rate, indices, z, gamma_, Kc, Kp, acc, MC);

    vg_finalize_kernel<<<(4 * NCELL + 255) / 256, 256, 0, stream>>>(
        acc, rate, indices, Kc, Kp, (float*)d_out, MC);
}